// Round 1
// 219.419 us; speedup vs baseline: 1.0373x; 1.0373x over previous
//
#include <hip/hip_runtime.h>

// ws layout (floats):
//   [128..202]       quantized w_conv (75)
//   [256..44159]     quantized w_fc1 TRANSPOSED [j=343][o=128]
//   [44160..44671]   quantized w_fc2 [4][128]
#define WS_WCONV   128
#define WS_W1T     256
#define WS_W2      44160

__device__ __forceinline__ float q4(float w, float s) {
  if (s <= 0.f) return 0.f;
  float r = rintf(w / s);                     // round-half-even == jnp.round
  r = fminf(fmaxf(r, -8.f), 7.f);
  return r * s;
}

// Single quant dispatch (R3-proven, absmax 0): every fc1 block redundantly
// computes global max|w1| (172 KB, L2/LLC-cheap). Block 88: conv + fc2.
__global__ __launch_bounds__(256) void quant_all(
    const float* __restrict__ wconv, const float* __restrict__ w1,
    const float* __restrict__ w2, float* __restrict__ ws) {
  __shared__ float red[256];
  int b = blockIdx.x, t = threadIdx.x;
  if (b < 88) {
    const float4* w4 = (const float4*)w1;     // 43904/4 == 10976
    float m = 0.f;
    for (int i = t; i < 10976; i += 256) {
      float4 v = w4[i];
      m = fmaxf(m, fmaxf(fmaxf(fabsf(v.x), fabsf(v.y)),
                         fmaxf(fabsf(v.z), fabsf(v.w))));
    }
    red[t] = m;
    __syncthreads();
    for (int s = 128; s > 0; s >>= 1) {
      if (t < s) red[t] = fmaxf(red[t], red[t + s]);
      __syncthreads();
    }
    float s = red[0] * (1.0f / 7.0f);
    #pragma unroll
    for (int k = 0; k < 2; ++k) {
      int idx = b * 512 + k * 256 + t;
      if (idx < 43904) {
        float q = q4(w1[idx], s);
        int o = idx / 343;
        int j = idx - o * 343;
        ws[WS_W1T + j * 128 + o] = q;         // transpose for coalesced FC1
      }
    }
  } else {
    float mc = (t < 75) ? fabsf(wconv[t]) : 0.f;
    float m2 = 0.f;
    for (int i = t; i < 512; i += 256) m2 = fmaxf(m2, fabsf(w2[i]));
    red[t] = mc;
    __syncthreads();
    for (int s = 128; s > 0; s >>= 1) {
      if (t < s) red[t] = fmaxf(red[t], red[t + s]);
      __syncthreads();
    }
    float sc = red[0] * (1.0f / 7.0f);
    __syncthreads();
    red[t] = m2;
    __syncthreads();
    for (int s = 128; s > 0; s >>= 1) {
      if (t < s) red[t] = fmaxf(red[t], red[t + s]);
      __syncthreads();
    }
    float s2 = red[0] * (1.0f / 7.0f);
    if (t < 75) ws[WS_WCONV + t] = q4(wconv[t], sc);
    #pragma unroll
    for (int k = 0; k < 2; ++k) {
      int idx = k * 256 + t;
      ws[WS_W2 + idx] = q4(w2[idx], s2);
    }
  }
}

// ---- swizzled LDS x-tile -------------------------------------------------
// Layout: row (depth d, line h) at xs[(d*16+h)*32 ..], 32-float padded rows.
// Quad q (float4 #q) of row r stored at quad q ^ (r&7)  (G4 XOR swizzle):
// conv's ds_read_b128 lanes (49 active, same column-quad, different rows)
// then spread over all 8 quad slots -> structural floor, no 7-way conflict.
__device__ __forceinline__ void scat1(float* xs, int r, int c, float v) {
  xs[(r << 5) + (((c >> 2) ^ (r & 7)) << 2) + (c & 3)] = v;
}

// Scatter one flat float4 (chunk-local f4 index i over 31-float source rows)
// into the swizzled tile. e/31 via magic mul: exact for e < 9517 (max 9420).
__device__ __forceinline__ void scatter4(float* xs, float4 v, int i) {
  int e0 = i << 2;
  int r  = (int)(((unsigned)e0 * 67651u) >> 21);   // e0/31
  int c  = e0 - r * 31;
  int c1 = c + 1, r1 = r; if (c1 >= 31) { c1 -= 31; ++r1; }
  int c2 = c + 2, r2 = r; if (c2 >= 31) { c2 -= 31; ++r2; }
  int c3 = c + 3, r3 = r; if (c3 >= 31) { c3 -= 31; ++r3; }
  scat1(xs, r,  c,  v.x);
  scat1(xs, r1, c1, v.y);
  scat1(xs, r2, c2, v.z);
  scat1(xs, r3, c3, v.w);
}

// Conv inner phase (R3-proven fma order preserved -> absmax stays 0).
// npf threads, pd = pd_off + t/49. xs holds chunk depths at local index,
// padded/swizzled layout; per (dd,hh) the 7-float window [4pw..4pw+6] is two
// aligned ds_read_b128 at quads pw^s and (pw+1)^s.
__device__ __forceinline__ void conv_phase(
    const float* __restrict__ xs, const float* __restrict__ wq,
    int t, int npf, int pd_off, float bc, float* __restrict__ feat) {
  if (t >= npf) return;
  int pdl = t / 49;
  int rr  = t - pdl * 49;
  int ph  = rr / 7;
  int pw  = rr - ph * 7;
  float c[2][2][2];                           // [odp][ohp][owp]
  #pragma unroll
  for (int i = 0; i < 8; ++i) ((float*)c)[i] = 0.f;
  int h0 = 2 * ph;
  int dbase = pdl * 2048;                     // 4 depths * 512
  #pragma unroll
  for (int dd = 0; dd < 7; ++dd) {
    int rb = dbase + dd * 512;
    #pragma unroll
    for (int hh = 0; hh < 4; ++hh) {
      int h = h0 + hh;
      int rowb = rb + (h << 5);
      int sw = h & 7;
      float4 A = *(const float4*)(xs + rowb + ((pw ^ sw) << 2));
      float4 B = *(const float4*)(xs + rowb + (((pw + 1) ^ sw) << 2));
      float row[7] = {A.x, A.y, A.z, A.w, B.x, B.y, B.z};
      #pragma unroll
      for (int odp = 0; odp < 2; ++odp) {
        int kd = dd - 2 * odp;
        if (kd < 0 || kd > 4) continue;       // folds at compile time
        #pragma unroll
        for (int ohp = 0; ohp < 2; ++ohp) {
          int kh = hh - ohp;
          if (kh < 0 || kh > 2) continue;     // folds at compile time
          #pragma unroll
          for (int owp = 0; owp < 2; ++owp) {
            float a = c[odp][ohp][owp];
            #pragma unroll
            for (int kw = 0; kw < 5; ++kw)
              a = fmaf(row[2 * owp + kw], wq[kd * 15 + kh * 5 + kw], a);
            c[odp][ohp][owp] = a;
          }
        }
      }
    }
  }
  float m = ((float*)c)[0];
  #pragma unroll
  for (int i = 1; i < 8; ++i) m = fmaxf(m, ((float*)c)[i]);
  feat[(pdl + pd_off) * 49 + rr] = m + bc;
}

// Fully fused: conv+pool (two depth chunks) + FC1 + FC2 + softmax.
// One block per batch. LDS: 9728 (padded/swizzled xs) + 344 (feat) floats =
// 40288 B -> still 4 blocks/CU. FC scratch (fc1p/a1/s2) aliases into xs
// (xs dead after P4). Chunk-2 global loads issue BEFORE P2 conv (T14 split):
// HBM latency hides under conv, ds_writes land after the barrier.
__global__ __launch_bounds__(256, 4) void fused_net(
    const float* __restrict__ x, const float* __restrict__ bconv,
    const float* __restrict__ ws, const float* __restrict__ bfc1,
    const float* __restrict__ bfc2, float* __restrict__ out) {
  __shared__ alignas(16) float xs[9728];      // 19 depths * 16 rows * 32
  __shared__ alignas(16) float feat[344];     // +1: feat[343]=0 pads FC1 quads
  float* fc1p = xs;                           // alias: live only after P4
  float* a1   = xs + 128;
  float* s2   = xs + 256;
  int t = threadIdx.x;
  int b = blockIdx.x;
  const float* wq = ws + WS_WCONV;
  float bc = bconv[0];

  // P1: stage depths 0..18 (2356 flat float4, coalesced) -> swizzled xs
  {
    const float4* src = (const float4*)(x + (size_t)b * 15376);
    float4 v0 = src[t];
    float4 v1 = src[t + 256];
    float4 v2 = src[t + 512];
    float4 v3 = src[t + 768];
    float4 v4 = src[t + 1024];
    float4 v5 = src[t + 1280];
    float4 v6 = src[t + 1536];
    float4 v7 = src[t + 1792];
    float4 v8 = src[t + 2048];
    bool has9 = (t + 2304) < 2356;
    float4 v9 = has9 ? src[t + 2304] : make_float4(0.f, 0.f, 0.f, 0.f);
    scatter4(xs, v0, t);
    scatter4(xs, v1, t + 256);
    scatter4(xs, v2, t + 512);
    scatter4(xs, v3, t + 768);
    scatter4(xs, v4, t + 1024);
    scatter4(xs, v5, t + 1280);
    scatter4(xs, v6, t + 1536);
    scatter4(xs, v7, t + 1792);
    scatter4(xs, v8, t + 2048);
    if (has9) scatter4(xs, v9, t + 2304);
    if (t == 0) feat[343] = 0.f;
  }
  __syncthreads();

  // Prefetch chunk 2 (depths 16..30: 1860 float4) into regs NOW; conv P2
  // runs while the loads are in flight (T14 issue-early / write-late).
  const float4* src2 = (const float4*)(x + (size_t)b * 15376 + 7936);
  float4 p0 = src2[t];
  float4 p1 = src2[t + 256];
  float4 p2 = src2[t + 512];
  float4 p3 = src2[t + 768];
  float4 p4 = src2[t + 1024];
  float4 p5 = src2[t + 1280];
  float4 p6 = src2[t + 1536];
  bool has7 = (t + 1792) < 1860;
  float4 p7 = has7 ? src2[t + 1792] : make_float4(0.f, 0.f, 0.f, 0.f);

  // P2: conv pd 0..3 (196 threads)
  conv_phase(xs, wq, t, 196, 0, bc, feat);
  __syncthreads();

  // P3: scatter chunk 2 (rows 0..239 overwritten; rows 240..303 stale, unread)
  scatter4(xs, p0, t);
  scatter4(xs, p1, t + 256);
  scatter4(xs, p2, t + 512);
  scatter4(xs, p3, t + 768);
  scatter4(xs, p4, t + 1024);
  scatter4(xs, p5, t + 1280);
  scatter4(xs, p6, t + 1536);
  if (has7) scatter4(xs, p7, t + 1792);
  __syncthreads();

  // P4: conv pd 4..6 (147 threads)
  conv_phase(xs, wq, t, 147, 4, bc, feat);
  __syncthreads();

  // P5: FC1 (343->128). g = j-half, o = output. Features read as b128 quads
  // (43 quads each half; g=1 tail uses feat[343]=0, w1T row 343 lands in
  // finite W2 region * 0.0 -> exact). w1T loads lane-coalesced.
  int g = t >> 7, o = t & 127;
  {
    const float* w1T = ws + WS_W1T;
    int j0 = g ? 172 : 0;
    const float4* f4 = (const float4*)&feat[j0];
    const float* wp = w1T + j0 * 128 + o;
    float q0 = 0.f, q1 = 0.f, q2 = 0.f, q3 = 0.f;
    for (int q = 0; q < 43; ++q) {
      float4 ff = f4[q];
      q0 = fmaf(ff.x, wp[0],   q0);
      q1 = fmaf(ff.y, wp[128], q1);
      q2 = fmaf(ff.z, wp[256], q2);
      q3 = fmaf(ff.w, wp[384], q3);
      wp += 512;
    }
    float acc = (q0 + q1) + (q2 + q3);
    if (g) fc1p[o] = acc;
    __syncthreads();
    if (!g) a1[o] = fmaxf(acc + fc1p[o] + bfc1[o], 0.f);
  }
  __syncthreads();

  // P6: FC2 (128->4) on one wave: lane = (kk,cls), shuffle-reduce over kk.
  if (t < 64) {
    int cls = t & 3, kk = t >> 2;             // kk 0..15, 8 k's each
    const float* w2p = ws + WS_W2 + cls * 128 + kk * 8;
    const float* av = a1 + kk * 8;
    float p = 0.f;
    #pragma unroll
    for (int i = 0; i < 8; ++i) p = fmaf(av[i], w2p[i], p);
    p += __shfl_down(p, 32);
    p += __shfl_down(p, 16);
    p += __shfl_down(p, 8);
    p += __shfl_down(p, 4);
    if (t < 4) s2[t] = p + bfc2[t];
  }
  __syncthreads();
  // P7: softmax + store
  if (t < 4) {
    float v0 = s2[0], v1 = s2[1], v2 = s2[2], v3 = s2[3];
    float m = fmaxf(fmaxf(v0, v1), fmaxf(v2, v3));
    float e0 = expf(v0 - m), e1 = expf(v1 - m);
    float e2 = expf(v2 - m), e3 = expf(v3 - m);
    float inv = 1.f / (e0 + e1 + e2 + e3);
    float mine = (t == 0) ? e0 : (t == 1) ? e1 : (t == 2) ? e2 : e3;
    out[b * 4 + t] = mine * inv;
  }
}

extern "C" void kernel_launch(void* const* d_in, const int* in_sizes, int n_in,
                              void* d_out, int out_size, void* d_ws, size_t ws_size,
                              hipStream_t stream) {
  const float* x     = (const float*)d_in[0];
  const float* wconv = (const float*)d_in[1];
  const float* bconv = (const float*)d_in[2];
  const float* wfc1  = (const float*)d_in[3];
  const float* bfc1  = (const float*)d_in[4];
  const float* wfc2  = (const float*)d_in[5];
  const float* bfc2  = (const float*)d_in[6];
  float* out = (float*)d_out;
  float* ws  = (float*)d_ws;

  quant_all<<<89, 256, 0, stream>>>(wconv, wfc1, wfc2, ws);
  fused_net<<<2048, 256, 0, stream>>>(x, bconv, ws, bfc1, bfc2, out);
}